// Round 26
// baseline (42.933 us; speedup 1.0000x reference)
//
#include <hip/hip_runtime.h>
#include <hip/hip_fp16.h>

// SSIM loss — round 26: r25 + asm-batched LDS read trains.
// Same cure as r22's global loads, applied to lgkm: the h-phase's 6
// ds_read_b128 (3 rt x fa/fb) and v-phase's 8 ds_read_b64 are each issued
// in ONE asm blob (imm offsets off a single base) with the lgkmcnt(0)
// inside the blob -> one latency exposure per phase instead of 6/8.
// Outputs are blob-defined, so consumers are data-dependent (no rule-18
// hazard). Everything else identical to r25: 3 tiles/block, grid 2048
// (exact 2-round packing), cross-tile global-load pipeline, operand-swapped
// h-MFMA, b64 col-major stores, v windows {0,12}. 512 thr, LDS 37.9KB.

#define IMGH 512
#define IMGW 512
#define TW 64
#define TH 32
#define GX 8
#define GY 16
#define GZT 16             // grid.z ; each block does 3 z-planes (48 total)
#define NBLOCKS (GX * GY * GZT)  // 2048
#define NPIX (16 * 3 * 512 * 512)
#define C1F 1.0e-4f
#define C2F 9.0e-4f

#define INSTRIDE 88        // halfs/row (176B, b128-aligned reads)
#define INPLANE (42 * INSTRIDE)
#define VSTRIDE 44         // halfs/col (88B); rows 42,43 zeroed for window 12
#define VPLANE (64 * VSTRIDE)
#define WBASE 34

// Gaussian weights, sigma=1.5, ws=11 (validated r1-r25).
#define W0 0.0010283818f
#define W1 0.0075987503f
#define W2 0.0360007547f
#define W3 0.1093606960f
#define W4 0.2130055367f
#define W5 0.2660117184f

typedef _Float16 half8v __attribute__((ext_vector_type(8)));
typedef float f32x4 __attribute__((ext_vector_type(4)));
union H8 { half8v v; __half2 h2[4]; float4 f4; unsigned u[4]; uint2 u2[2]; };

static __device__ __forceinline__ __half2 pkrtz(float a, float b) {
    auto r = __builtin_amdgcn_cvt_pkrtz(a, b);   // __fp16 ext_vector(2)
    return *reinterpret_cast<__half2*>(&r);
}
static __device__ __forceinline__ float wval(int i) {
    const float W[11] = {W0, W1, W2, W3, W4, W5, W4, W3, W2, W1, W0};
    float w = 0.f;
#pragma unroll
    for (int j = 0; j < 11; ++j) w = (i == WBASE + j) ? W[j] : w;
    return w;
}

__global__ __launch_bounds__(512, 6)
void ssim_tile(const float* __restrict__ img1, const float* __restrict__ img2,
               float* __restrict__ partials) {
    __shared__ _Float16 sWext[96];          // [WBASE..WBASE+10] = W[0..10]
    __shared__ _Float16 sIn[2 * INPLANE];   // 14,784 B : a | b
    __shared__ _Float16 sV[4 * VPLANE];     // 22,528 B : col-major, 44 rows
    __shared__ float wsum[8];

    const int tid  = threadIdx.x;
    const int lane = tid & 63;
    const int wv   = tid >> 6;
    const int lr = lane & 15;
    const int kc = lane >> 4;
    const int r0 = blockIdx.y * TH;
    const int c0 = blockIdx.x * TW;
    const bool fast = (blockIdx.x >= 1) & (blockIdx.x <= GX - 2) &
                      (blockIdx.y >= 1) & (blockIdx.y <= GY - 2);

    // prep item geometry (tid < 420)
    const int prow = (unsigned)tid / 10u;
    const int pch  = tid - prow * 10;
    const int pgr  = r0 - 5 + prow;
    const int pgc  = c0 - 8 + 8 * pch;
    const bool pok = (unsigned)pgr < IMGH && (unsigned)pgc < IMGW;
    const size_t goff = (size_t)pgr * IMGW + pgc;

    // per-tile image base (3 consecutive z-planes)
    const float* pa4[3];
    const float* pb4[3];
#pragma unroll
    for (int t = 0; t < 3; ++t) {
        const size_t pbase = ((size_t)blockIdx.z * 3 + t) * (IMGH * IMGW);
        pa4[t] = img1 + pbase;
        pb4[t] = img2 + pbase;
    }

    // aux: weight table + zero sV rows 42,43 (wave 7; prep threads are <420)
    if (tid >= 448) {
        const int t = tid - 448;
        sWext[t] = (_Float16)wval(t);
        if (t < 32) sWext[t + 64] = (_Float16)wval(t + 64);
#pragma unroll
        for (int j = 0; j < 4; ++j) {
            const int w = t + (j << 6);
            const int q = w >> 6, col = w & 63;
            *reinterpret_cast<unsigned*>(&sV[q * VPLANE + col * VSTRIDE + 42]) = 0u;
        }
    }

    f32x4 va1, va2, vb1, vb2;       // in-flight prep load registers
    const bool pipeline = fast && (tid < 420);

    // prologue: issue tile-0 loads
    if (pipeline) {
        const float* pa = pa4[0] + goff;
        const float* pb = pb4[0] + goff;
        asm volatile(
            "global_load_dwordx4 %0, %4, off\n\t"
            "global_load_dwordx4 %1, %4, off offset:16\n\t"
            "global_load_dwordx4 %2, %5, off\n\t"
            "global_load_dwordx4 %3, %5, off offset:16"
            : "=&v"(va1), "=&v"(va2), "=&v"(vb1), "=&v"(vb2)
            : "v"(pa), "v"(pb)
            : "memory");
    }

    half8v Wh, Av0, Av1;
    float lsum = 0.f;

#pragma unroll
    for (int t = 0; t < 3; ++t) {
        // ---- convert + store sIn(t) ----
        if (tid < 420) {
            if (pipeline) {
                asm volatile("s_waitcnt vmcnt(0)"
                             : "+v"(va1), "+v"(va2), "+v"(vb1), "+v"(vb2));
            } else {
                va1 = (f32x4){0.f, 0.f, 0.f, 0.f};
                va2 = vb1 = vb2 = va1;
                if (pok) {
                    const float* pa = pa4[t] + goff;
                    const float* pb = pb4[t] + goff;
                    va1 = *reinterpret_cast<const f32x4*>(pa);
                    va2 = *reinterpret_cast<const f32x4*>(pa + 4);
                    vb1 = *reinterpret_cast<const f32x4*>(pb);
                    vb2 = *reinterpret_cast<const f32x4*>(pb + 4);
                }
            }
            const int off = prow * INSTRIDE + 8 * pch;
            H8 ha, hb;
            ha.h2[0] = pkrtz(va1[0], va1[1]); ha.h2[1] = pkrtz(va1[2], va1[3]);
            ha.h2[2] = pkrtz(va2[0], va2[1]); ha.h2[3] = pkrtz(va2[2], va2[3]);
            hb.h2[0] = pkrtz(vb1[0], vb1[1]); hb.h2[1] = pkrtz(vb1[2], vb1[3]);
            hb.h2[2] = pkrtz(vb2[0], vb2[1]); hb.h2[3] = pkrtz(vb2[2], vb2[3]);
            *reinterpret_cast<float4*>(&sIn[off]) = ha.f4;
            *reinterpret_cast<float4*>(&sIn[INPLANE + off]) = hb.f4;
        }
        __syncthreads();                    // barrier A: sIn ready, v(t-1) done

        // issue loads for tile t+1 (fly under h+v of tile t)
        if (t < 2 && pipeline) {
            const float* pa = pa4[t + 1] + goff;
            const float* pb = pb4[t + 1] + goff;
            asm volatile(
                "global_load_dwordx4 %0, %4, off\n\t"
                "global_load_dwordx4 %1, %4, off offset:16\n\t"
                "global_load_dwordx4 %2, %5, off\n\t"
                "global_load_dwordx4 %3, %5, off offset:16"
                : "=&v"(va1), "=&v"(va2), "=&v"(vb1), "=&v"(vb2)
                : "v"(pa), "v"(pb)
                : "memory");
        }
        if (t == 0) {                       // weight fragments (sWext ready)
            const int bi = (kc << 3) - lr + WBASE;
#pragma unroll
            for (int e = 0; e < 8; ++e) Wh[e]  = sWext[bi - 3 + e];  // W[k-n-3]
#pragma unroll
            for (int e = 0; e < 8; ++e) Av0[e] = sWext[bi + e];      // W[k-m]
#pragma unroll
            for (int e = 0; e < 8; ++e) Av1[e] = sWext[bi - 4 + e];  // W[k-m-4]
        }

        // ---- h-phase: 24 half-positions (rt,ct,qp), 3 per wave ----
        // All 6 b128 reads (3 rt x fa/fb) in ONE asm blob, imm offsets:
        // rt 0/16/26 rows -> +0/2816/4576 B; fb = +INPLANE*2 = 7392 B.
        {
            const int ct = (wv >> 1) & 3;
            const int qp = wv & 1;
            const unsigned hbase = (unsigned)(size_t)
                &sIn[lr * INSTRIDE + 16 * ct + (kc << 3)];
            H8 fa[3], fb[3];
            asm volatile(
                "ds_read_b128 %0, %6\n\t"
                "ds_read_b128 %1, %6 offset:2816\n\t"
                "ds_read_b128 %2, %6 offset:4576\n\t"
                "ds_read_b128 %3, %6 offset:7392\n\t"
                "ds_read_b128 %4, %6 offset:10208\n\t"
                "ds_read_b128 %5, %6 offset:11968\n\t"
                "s_waitcnt lgkmcnt(0)"
                : "=&v"(fa[0].f4), "=&v"(fa[1].f4), "=&v"(fa[2].f4),
                  "=&v"(fb[0].f4), "=&v"(fb[1].f4), "=&v"(fb[2].f4)
                : "v"(hbase));
#pragma unroll
            for (int rt = 0; rt < 3; ++rt) {
                const int rb = (rt == 0) ? 0 : (rt == 1 ? 16 : 26);
                H8 f0, f1;
                if (qp == 0) {
                    f0 = fa[rt]; f1 = fb[rt];
                } else {
#pragma unroll
                    for (int u = 0; u < 4; ++u) {
                        f0.h2[u] = __hfma2(fa[rt].h2[u], fa[rt].h2[u],
                                           __hmul2(fb[rt].h2[u], fb[rt].h2[u]));
                        f1.h2[u] = __hmul2(fa[rt].h2[u], fb[rt].h2[u]);
                    }
                }
                f32x4 d0 = {0.f, 0.f, 0.f, 0.f}, d1 = d0;
                d0 = __builtin_amdgcn_mfma_f32_16x16x32_f16(f0.v, Wh, d0, 0, 0, 0);
                d1 = __builtin_amdgcn_mfma_f32_16x16x32_f16(f1.v, Wh, d1, 0, 0, 0);
                const int p0 = qp * 2, p1 = qp * 2 + 1;
                const int vb = (16 * ct + lr) * VSTRIDE + rb + (kc << 2);
                uint2 s0, s1;
                __half2 h;
                h = pkrtz(d0[0], d0[1]); s0.x = *reinterpret_cast<unsigned*>(&h);
                h = pkrtz(d0[2], d0[3]); s0.y = *reinterpret_cast<unsigned*>(&h);
                h = pkrtz(d1[0], d1[1]); s1.x = *reinterpret_cast<unsigned*>(&h);
                h = pkrtz(d1[2], d1[3]); s1.y = *reinterpret_cast<unsigned*>(&h);
                if (rt < 2) {
                    *reinterpret_cast<uint2*>(&sV[p0 * VPLANE + vb]) = s0;
                    *reinterpret_cast<uint2*>(&sV[p1 * VPLANE + vb]) = s1;
                } else {   // rb=26: 4B-aligned only
                    unsigned* q0 = reinterpret_cast<unsigned*>(&sV[p0 * VPLANE + vb]);
                    unsigned* q1 = reinterpret_cast<unsigned*>(&sV[p1 * VPLANE + vb]);
                    q0[0] = s0.x; q0[1] = s0.y;
                    q1[0] = s1.x; q1[1] = s1.y;
                }
            }
        }
        __syncthreads();                    // barrier B: sV ready, sIn free

        // ---- v-phase: ct2 = wv&3, rt2 = wv>>2; one 8-read asm blob ----
        // Offsets: plane q -> q*5632 B; second b64 chunk -> +8 B.
        {
            const int ct2 = wv & 3;
            const int rt2 = wv >> 2;
            const int w0 = rt2 ? 12 : 0;
            const half8v Avx = rt2 ? Av1 : Av0;
            const unsigned vba = (unsigned)(size_t)
                &sV[(16 * ct2 + lr) * VSTRIDE + w0 + (kc << 3)];
            uint2 r0v, r1v, r2v, r3v, r4v, r5v, r6v, r7v;
            asm volatile(
                "ds_read_b64 %0, %8\n\t"
                "ds_read_b64 %1, %8 offset:8\n\t"
                "ds_read_b64 %2, %8 offset:5632\n\t"
                "ds_read_b64 %3, %8 offset:5640\n\t"
                "ds_read_b64 %4, %8 offset:11264\n\t"
                "ds_read_b64 %5, %8 offset:11272\n\t"
                "ds_read_b64 %6, %8 offset:16896\n\t"
                "ds_read_b64 %7, %8 offset:16904\n\t"
                "s_waitcnt lgkmcnt(0)"
                : "=&v"(r0v), "=&v"(r1v), "=&v"(r2v), "=&v"(r3v),
                  "=&v"(r4v), "=&v"(r5v), "=&v"(r6v), "=&v"(r7v)
                : "v"(vba));
            H8 c0, c1, c2, c3;
            c0.u2[0] = r0v; c0.u2[1] = r1v;
            c1.u2[0] = r2v; c1.u2[1] = r3v;
            c2.u2[0] = r4v; c2.u2[1] = r5v;
            c3.u2[0] = r6v; c3.u2[1] = r7v;
            f32x4 d0 = {0.f, 0.f, 0.f, 0.f}, d1 = d0, d2 = d0, d3 = d0;
            d0 = __builtin_amdgcn_mfma_f32_16x16x32_f16(Avx, c0.v, d0, 0, 0, 0);
            d1 = __builtin_amdgcn_mfma_f32_16x16x32_f16(Avx, c1.v, d1, 0, 0, 0);
            d2 = __builtin_amdgcn_mfma_f32_16x16x32_f16(Avx, c2.v, d2, 0, 0, 0);
            d3 = __builtin_amdgcn_mfma_f32_16x16x32_f16(Avx, c3.v, d3, 0, 0, 0);
#pragma unroll
            for (int r = 0; r < 4; ++r) {
                const float mu1 = d0[r], mu2 = d1[r], S = d2[r], eab = d3[r];
                const float mu11 = mu1 * mu1, mu22 = mu2 * mu2, mu12 = mu1 * mu2;
                const float s12 = eab - mu12;
                const float num = (2.f * mu12 + C1F) * (2.f * s12 + C2F);
                const float den = (mu11 + mu22 + C1F) * ((S - mu11 - mu22) + C2F);
                lsum += num * __builtin_amdgcn_rcpf(den);
            }
        }
    }

    // ---- deterministic block reduction (8 waves) ----
#pragma unroll
    for (int off = 32; off > 0; off >>= 1) lsum += __shfl_down(lsum, off, 64);
    if (lane == 0) wsum[wv] = lsum;
    __syncthreads();
    if (tid == 0) {
        float t = 0.f;
#pragma unroll
        for (int w = 0; w < 8; ++w) t += wsum[w];
        partials[((size_t)blockIdx.z * GY + blockIdx.y) * GX + blockIdx.x] = t;
    }
}

__global__ __launch_bounds__(1024)
void ssim_reduce(const float* __restrict__ partials, float* __restrict__ out, int n) {
    __shared__ float lds[1024];
    float s = 0.f;
    for (int i = threadIdx.x; i < n; i += 1024) s += partials[i];
    lds[threadIdx.x] = s;
    __syncthreads();
    for (int off = 512; off > 0; off >>= 1) {
        if ((int)threadIdx.x < off) lds[threadIdx.x] += lds[threadIdx.x + off];
        __syncthreads();
    }
    if (threadIdx.x == 0) out[0] = 1.f - lds[0] / (float)NPIX;
}

extern "C" void kernel_launch(void* const* d_in, const int* in_sizes, int n_in,
                              void* d_out, int out_size, void* d_ws, size_t ws_size,
                              hipStream_t stream) {
    const float* img1 = (const float*)d_in[0];
    const float* img2 = (const float*)d_in[1];
    float* out = (float*)d_out;
    float* partials = (float*)d_ws;

    dim3 grid(GX, GY, GZT);
    ssim_tile<<<grid, 512, 0, stream>>>(img1, img2, partials);
    ssim_reduce<<<1, 1024, 0, stream>>>(partials, out, NBLOCKS);
}

// Round 27
// 37.656 us; speedup vs baseline: 1.1401x; 1.1401x over previous
//
#include <hip/hip_runtime.h>
#include <hip/hip_fp16.h>

// SSIM loss — round 27: REVERT to r25 (best verified: 37.8us, absmax 0.0).
// r26's asm-batched LDS reads spilled (WRITE_SIZE 66KB->16.4MB scratch) and
// regressed to 42.9us — falsified per pre-commitment; this is the final
// structure. Design: 3 z-plane tiles/block, grid 8x16x16=2048 = exactly
// 2 full residency rounds (4 blocks/CU x 256 CU); cross-tile pipelined
// prep loads (asm blob: 4x global_load_dwordx4 issued early, vmcnt(0)
// waited late under h+v cover); operand-swapped h-MFMA (D rows = image
// rows -> b64 col-major sV stores); q-pair split; v windows {0,12} with
// rows 42/43 zeroed; lane-local SSIM on f32 accumulators; deterministic
// two-stage reduction. 512 thr, LDS 37.9KB, 4 blocks/CU.

#define IMGH 512
#define IMGW 512
#define TW 64
#define TH 32
#define GX 8
#define GY 16
#define GZT 16             // grid.z ; each block does 3 z-planes (48 total)
#define NBLOCKS (GX * GY * GZT)  // 2048
#define NPIX (16 * 3 * 512 * 512)
#define C1F 1.0e-4f
#define C2F 9.0e-4f

#define INSTRIDE 88        // halfs/row (176B, b128-aligned reads)
#define INPLANE (42 * INSTRIDE)
#define VSTRIDE 44         // halfs/col (88B); rows 42,43 zeroed for window 12
#define VPLANE (64 * VSTRIDE)
#define WBASE 34

// Gaussian weights, sigma=1.5, ws=11 (validated r1-r25).
#define W0 0.0010283818f
#define W1 0.0075987503f
#define W2 0.0360007547f
#define W3 0.1093606960f
#define W4 0.2130055367f
#define W5 0.2660117184f

typedef _Float16 half8v __attribute__((ext_vector_type(8)));
typedef float f32x4 __attribute__((ext_vector_type(4)));
union H8 { half8v v; __half2 h2[4]; float4 f4; unsigned u[4]; };

static __device__ __forceinline__ __half2 pkrtz(float a, float b) {
    auto r = __builtin_amdgcn_cvt_pkrtz(a, b);   // __fp16 ext_vector(2)
    return *reinterpret_cast<__half2*>(&r);
}
static __device__ __forceinline__ float wval(int i) {
    const float W[11] = {W0, W1, W2, W3, W4, W5, W4, W3, W2, W1, W0};
    float w = 0.f;
#pragma unroll
    for (int j = 0; j < 11; ++j) w = (i == WBASE + j) ? W[j] : w;
    return w;
}

__global__ __launch_bounds__(512, 6)
void ssim_tile(const float* __restrict__ img1, const float* __restrict__ img2,
               float* __restrict__ partials) {
    __shared__ _Float16 sWext[96];          // [WBASE..WBASE+10] = W[0..10]
    __shared__ _Float16 sIn[2 * INPLANE];   // 14,784 B : a | b
    __shared__ _Float16 sV[4 * VPLANE];     // 22,528 B : col-major, 44 rows
    __shared__ float wsum[8];

    const int tid  = threadIdx.x;
    const int lane = tid & 63;
    const int wv   = tid >> 6;
    const int lr = lane & 15;
    const int kc = lane >> 4;
    const int r0 = blockIdx.y * TH;
    const int c0 = blockIdx.x * TW;
    const bool fast = (blockIdx.x >= 1) & (blockIdx.x <= GX - 2) &
                      (blockIdx.y >= 1) & (blockIdx.y <= GY - 2);

    // prep item geometry (tid < 420)
    const int prow = (unsigned)tid / 10u;
    const int pch  = tid - prow * 10;
    const int pgr  = r0 - 5 + prow;
    const int pgc  = c0 - 8 + 8 * pch;
    const bool pok = (unsigned)pgr < IMGH && (unsigned)pgc < IMGW;
    const size_t goff = (size_t)pgr * IMGW + pgc;

    // per-tile image base (3 consecutive z-planes)
    const float* pa4[3];
    const float* pb4[3];
#pragma unroll
    for (int t = 0; t < 3; ++t) {
        const size_t pbase = ((size_t)blockIdx.z * 3 + t) * (IMGH * IMGW);
        pa4[t] = img1 + pbase;
        pb4[t] = img2 + pbase;
    }

    // aux: weight table + zero sV rows 42,43 (wave 7; prep threads are <420)
    if (tid >= 448) {
        const int t = tid - 448;
        sWext[t] = (_Float16)wval(t);
        if (t < 32) sWext[t + 64] = (_Float16)wval(t + 64);
#pragma unroll
        for (int j = 0; j < 4; ++j) {
            const int w = t + (j << 6);
            const int q = w >> 6, col = w & 63;
            *reinterpret_cast<unsigned*>(&sV[q * VPLANE + col * VSTRIDE + 42]) = 0u;
        }
    }

    f32x4 va1, va2, vb1, vb2;       // in-flight prep load registers
    const bool pipeline = fast && (tid < 420);

    // prologue: issue tile-0 loads
    if (pipeline) {
        const float* pa = pa4[0] + goff;
        const float* pb = pb4[0] + goff;
        asm volatile(
            "global_load_dwordx4 %0, %4, off\n\t"
            "global_load_dwordx4 %1, %4, off offset:16\n\t"
            "global_load_dwordx4 %2, %5, off\n\t"
            "global_load_dwordx4 %3, %5, off offset:16"
            : "=&v"(va1), "=&v"(va2), "=&v"(vb1), "=&v"(vb2)
            : "v"(pa), "v"(pb)
            : "memory");
    }

    half8v Wh, Av0, Av1;
    float lsum = 0.f;

#pragma unroll
    for (int t = 0; t < 3; ++t) {
        // ---- convert + store sIn(t) ----
        if (tid < 420) {
            if (pipeline) {
                asm volatile("s_waitcnt vmcnt(0)"
                             : "+v"(va1), "+v"(va2), "+v"(vb1), "+v"(vb2));
            } else {
                va1 = (f32x4){0.f, 0.f, 0.f, 0.f};
                va2 = vb1 = vb2 = va1;
                if (pok) {
                    const float* pa = pa4[t] + goff;
                    const float* pb = pb4[t] + goff;
                    va1 = *reinterpret_cast<const f32x4*>(pa);
                    va2 = *reinterpret_cast<const f32x4*>(pa + 4);
                    vb1 = *reinterpret_cast<const f32x4*>(pb);
                    vb2 = *reinterpret_cast<const f32x4*>(pb + 4);
                }
            }
            const int off = prow * INSTRIDE + 8 * pch;
            H8 ha, hb;
            ha.h2[0] = pkrtz(va1[0], va1[1]); ha.h2[1] = pkrtz(va1[2], va1[3]);
            ha.h2[2] = pkrtz(va2[0], va2[1]); ha.h2[3] = pkrtz(va2[2], va2[3]);
            hb.h2[0] = pkrtz(vb1[0], vb1[1]); hb.h2[1] = pkrtz(vb1[2], vb1[3]);
            hb.h2[2] = pkrtz(vb2[0], vb2[1]); hb.h2[3] = pkrtz(vb2[2], vb2[3]);
            *reinterpret_cast<float4*>(&sIn[off]) = ha.f4;
            *reinterpret_cast<float4*>(&sIn[INPLANE + off]) = hb.f4;
        }
        __syncthreads();                    // barrier A: sIn ready, v(t-1) done

        // issue loads for tile t+1 (fly under h+v of tile t)
        if (t < 2 && pipeline) {
            const float* pa = pa4[t + 1] + goff;
            const float* pb = pb4[t + 1] + goff;
            asm volatile(
                "global_load_dwordx4 %0, %4, off\n\t"
                "global_load_dwordx4 %1, %4, off offset:16\n\t"
                "global_load_dwordx4 %2, %5, off\n\t"
                "global_load_dwordx4 %3, %5, off offset:16"
                : "=&v"(va1), "=&v"(va2), "=&v"(vb1), "=&v"(vb2)
                : "v"(pa), "v"(pb)
                : "memory");
        }
        if (t == 0) {                       // weight fragments (sWext ready)
            const int bi = (kc << 3) - lr + WBASE;
#pragma unroll
            for (int e = 0; e < 8; ++e) Wh[e]  = sWext[bi - 3 + e];  // W[k-n-3]
#pragma unroll
            for (int e = 0; e < 8; ++e) Av0[e] = sWext[bi + e];      // W[k-m]
#pragma unroll
            for (int e = 0; e < 8; ++e) Av1[e] = sWext[bi - 4 + e];  // W[k-m-4]
        }

        // ---- h-phase: 24 half-positions (rt,ct,qp), 3 per wave ----
        {
            const int ct = (wv >> 1) & 3;
            const int qp = wv & 1;
#pragma unroll
            for (int rt = 0; rt < 3; ++rt) {
                const int rb = (rt == 0) ? 0 : (rt == 1 ? 16 : 26);
                const int base = (rb + lr) * INSTRIDE + 16 * ct + (kc << 3);
                H8 fa, fb;
                fa.f4 = *reinterpret_cast<const float4*>(&sIn[base]);
                fb.f4 = *reinterpret_cast<const float4*>(&sIn[INPLANE + base]);
                H8 f0, f1;
                if (qp == 0) {
                    f0 = fa; f1 = fb;
                } else {
#pragma unroll
                    for (int u = 0; u < 4; ++u) {
                        f0.h2[u] = __hfma2(fa.h2[u], fa.h2[u],
                                           __hmul2(fb.h2[u], fb.h2[u]));
                        f1.h2[u] = __hmul2(fa.h2[u], fb.h2[u]);
                    }
                }
                f32x4 d0 = {0.f, 0.f, 0.f, 0.f}, d1 = d0;
                d0 = __builtin_amdgcn_mfma_f32_16x16x32_f16(f0.v, Wh, d0, 0, 0, 0);
                d1 = __builtin_amdgcn_mfma_f32_16x16x32_f16(f1.v, Wh, d1, 0, 0, 0);
                const int p0 = qp * 2, p1 = qp * 2 + 1;
                const int vb = (16 * ct + lr) * VSTRIDE + rb + (kc << 2);
                uint2 s0, s1;
                __half2 h;
                h = pkrtz(d0[0], d0[1]); s0.x = *reinterpret_cast<unsigned*>(&h);
                h = pkrtz(d0[2], d0[3]); s0.y = *reinterpret_cast<unsigned*>(&h);
                h = pkrtz(d1[0], d1[1]); s1.x = *reinterpret_cast<unsigned*>(&h);
                h = pkrtz(d1[2], d1[3]); s1.y = *reinterpret_cast<unsigned*>(&h);
                if (rt < 2) {
                    *reinterpret_cast<uint2*>(&sV[p0 * VPLANE + vb]) = s0;
                    *reinterpret_cast<uint2*>(&sV[p1 * VPLANE + vb]) = s1;
                } else {   // rb=26: 4B-aligned only
                    unsigned* q0 = reinterpret_cast<unsigned*>(&sV[p0 * VPLANE + vb]);
                    unsigned* q1 = reinterpret_cast<unsigned*>(&sV[p1 * VPLANE + vb]);
                    q0[0] = s0.x; q0[1] = s0.y;
                    q1[0] = s1.x; q1[1] = s1.y;
                }
            }
        }
        __syncthreads();                    // barrier B: sV ready, sIn free

        // ---- v-phase: ct2 = wv&3, rt2 = wv>>2; 2xb64 reads; SSIM ----
        {
            const int ct2 = wv & 3;
            const int rt2 = wv >> 2;
            const int w0 = rt2 ? 12 : 0;
            const half8v Avx = rt2 ? Av1 : Av0;
            const int vbase = (16 * ct2 + lr) * VSTRIDE + w0 + (kc << 3);
            auto vread = [&](int q) -> half8v {
                const _Float16* p = &sV[q * VPLANE + vbase];
                H8 c;
                *reinterpret_cast<uint2*>(&c.u[0]) =
                    *reinterpret_cast<const uint2*>(p);
                *reinterpret_cast<uint2*>(&c.u[2]) =
                    *reinterpret_cast<const uint2*>(p + 4);
                return c.v;
            };
            f32x4 d0 = {0.f, 0.f, 0.f, 0.f}, d1 = d0, d2 = d0, d3 = d0;
            d0 = __builtin_amdgcn_mfma_f32_16x16x32_f16(Avx, vread(0), d0, 0, 0, 0);
            d1 = __builtin_amdgcn_mfma_f32_16x16x32_f16(Avx, vread(1), d1, 0, 0, 0);
            d2 = __builtin_amdgcn_mfma_f32_16x16x32_f16(Avx, vread(2), d2, 0, 0, 0);
            d3 = __builtin_amdgcn_mfma_f32_16x16x32_f16(Avx, vread(3), d3, 0, 0, 0);
#pragma unroll
            for (int r = 0; r < 4; ++r) {
                const float mu1 = d0[r], mu2 = d1[r], S = d2[r], eab = d3[r];
                const float mu11 = mu1 * mu1, mu22 = mu2 * mu2, mu12 = mu1 * mu2;
                const float s12 = eab - mu12;
                const float num = (2.f * mu12 + C1F) * (2.f * s12 + C2F);
                const float den = (mu11 + mu22 + C1F) * ((S - mu11 - mu22) + C2F);
                lsum += num * __builtin_amdgcn_rcpf(den);
            }
        }
    }

    // ---- deterministic block reduction (8 waves) ----
#pragma unroll
    for (int off = 32; off > 0; off >>= 1) lsum += __shfl_down(lsum, off, 64);
    if (lane == 0) wsum[wv] = lsum;
    __syncthreads();
    if (tid == 0) {
        float t = 0.f;
#pragma unroll
        for (int w = 0; w < 8; ++w) t += wsum[w];
        partials[((size_t)blockIdx.z * GY + blockIdx.y) * GX + blockIdx.x] = t;
    }
}

__global__ __launch_bounds__(1024)
void ssim_reduce(const float* __restrict__ partials, float* __restrict__ out, int n) {
    __shared__ float lds[1024];
    float s = 0.f;
    for (int i = threadIdx.x; i < n; i += 1024) s += partials[i];
    lds[threadIdx.x] = s;
    __syncthreads();
    for (int off = 512; off > 0; off >>= 1) {
        if ((int)threadIdx.x < off) lds[threadIdx.x] += lds[threadIdx.x + off];
        __syncthreads();
    }
    if (threadIdx.x == 0) out[0] = 1.f - lds[0] / (float)NPIX;
}

extern "C" void kernel_launch(void* const* d_in, const int* in_sizes, int n_in,
                              void* d_out, int out_size, void* d_ws, size_t ws_size,
                              hipStream_t stream) {
    const float* img1 = (const float*)d_in[0];
    const float* img2 = (const float*)d_in[1];
    float* out = (float*)d_out;
    float* partials = (float*)d_ws;

    dim3 grid(GX, GY, GZT);
    ssim_tile<<<grid, 512, 0, stream>>>(img1, img2, partials);
    ssim_reduce<<<1, 1024, 0, stream>>>(partials, out, NBLOCKS);
}